// Round 1
// baseline (1937.855 us; speedup 1.0000x reference)
//
#include <hip/hip_runtime.h>
#include <hip/hip_bf16.h>

namespace {
constexpr int N_NODES = 10000;
constexpr int FIN  = 128;
constexpr int H1S  = 64;
constexpr int H2S  = 32;
constexpr int RREL = 65;
constexpr int EO   = 320000;
constexpr int ES   = 160000;
constexpr int NBR  = 4;
constexpr int BP   = 4096;
}

// ---------------- degree count: deg[dst*R + etype] += 1 ----------------
__global__ __launch_bounds__(256) void count_deg(const int* __restrict__ dstv,
                                                 const int* __restrict__ etv,
                                                 int E, float* __restrict__ deg) {
    int e = blockIdx.x * blockDim.x + threadIdx.x;
    if (e < E) atomicAdd(&deg[dstv[e] * RREL + etv[e]], 1.0f);
}

// ---------------- layer-1 messages: Fin=128 -> Fout=64 ----------------
// 16 threads per edge (each thread -> 4 outputs via float4 W loads); 16 edges/block.
__global__ __launch_bounds__(256) void rgcn_msg_l1(const float* __restrict__ x,
                                                   const int* __restrict__ srcv,
                                                   const int* __restrict__ dstv,
                                                   const int* __restrict__ etv,
                                                   int E,
                                                   const float* __restrict__ W,
                                                   const float* __restrict__ deg,
                                                   float* __restrict__ agg) {
    __shared__ float xs[16][FIN + 1];
    int tid  = threadIdx.x;
    int esub = tid >> 4;   // 0..15
    int og   = tid & 15;   // output group: outputs 4*og .. 4*og+3
    int e    = blockIdx.x * 16 + esub;
    bool valid = e < E;
    int ee = valid ? e : E - 1;
    int s = srcv[ee], d = dstv[ee], r = etv[ee];
    #pragma unroll
    for (int i = 0; i < 8; ++i)
        xs[esub][og + 16 * i] = x[(size_t)s * FIN + og + 16 * i];
    __syncthreads();
    float nrm = 1.0f / fmaxf(deg[d * RREL + r], 1.0f);
    const float* Wr = W + (size_t)r * FIN * H1S + og * 4;
    float4 acc = {0.f, 0.f, 0.f, 0.f};
    #pragma unroll 16
    for (int i = 0; i < FIN; ++i) {
        float xv = xs[esub][i];
        float4 w = *(const float4*)(Wr + (size_t)i * H1S);
        acc.x += xv * w.x; acc.y += xv * w.y; acc.z += xv * w.z; acc.w += xv * w.w;
    }
    if (valid) {
        float* ag = agg + (size_t)d * H1S + og * 4;
        atomicAdd(ag + 0, acc.x * nrm);
        atomicAdd(ag + 1, acc.y * nrm);
        atomicAdd(ag + 2, acc.z * nrm);
        atomicAdd(ag + 3, acc.w * nrm);
    }
}

// ---------------- layer-2 messages: Fin=64 -> Fout=32 ----------------
// 8 threads per edge (each thread -> 4 outputs); 32 edges/block.
__global__ __launch_bounds__(256) void rgcn_msg_l2(const float* __restrict__ x,
                                                   const int* __restrict__ srcv,
                                                   const int* __restrict__ dstv,
                                                   const int* __restrict__ etv,
                                                   int E,
                                                   const float* __restrict__ W,
                                                   const float* __restrict__ deg,
                                                   float* __restrict__ agg) {
    __shared__ float xs[32][H1S + 1];
    int tid  = threadIdx.x;
    int esub = tid >> 3;   // 0..31
    int og   = tid & 7;    // outputs 4*og .. 4*og+3
    int e    = blockIdx.x * 32 + esub;
    bool valid = e < E;
    int ee = valid ? e : E - 1;
    int s = srcv[ee], d = dstv[ee], r = etv[ee];
    #pragma unroll
    for (int i = 0; i < 8; ++i)
        xs[esub][og + 8 * i] = x[(size_t)s * H1S + og + 8 * i];
    __syncthreads();
    float nrm = 1.0f / fmaxf(deg[d * RREL + r], 1.0f);
    const float* Wr = W + (size_t)r * H1S * H2S + og * 4;
    float4 acc = {0.f, 0.f, 0.f, 0.f};
    #pragma unroll
    for (int i = 0; i < H1S; ++i) {
        float xv = xs[esub][i];
        float4 w = *(const float4*)(Wr + (size_t)i * H2S);
        acc.x += xv * w.x; acc.y += xv * w.y; acc.z += xv * w.z; acc.w += xv * w.w;
    }
    if (valid) {
        float* ag = agg + (size_t)d * H2S + og * 4;
        atomicAdd(ag + 0, acc.x * nrm);
        atomicAdd(ag + 1, acc.y * nrm);
        atomicAdd(ag + 2, acc.z * nrm);
        atomicAdd(ag + 3, acc.w * nrm);
    }
}

// ---------------- layer-1 finish: agg = relu(agg + x@root + b) ----------------
__global__ __launch_bounds__(256) void finish_l1(const float* __restrict__ x,
                                                 const float* __restrict__ root,
                                                 const float* __restrict__ bias,
                                                 float* __restrict__ agg, int n) {
    __shared__ float xs[16][FIN + 1];
    int tid = threadIdx.x;
    int vsub = tid >> 4, og = tid & 15;
    int v = blockIdx.x * 16 + vsub;
    bool valid = v < n;
    int vv = valid ? v : n - 1;
    #pragma unroll
    for (int i = 0; i < 8; ++i)
        xs[vsub][og + 16 * i] = x[(size_t)vv * FIN + og + 16 * i];
    __syncthreads();
    float* ag = agg + (size_t)vv * H1S + og * 4;
    float4 acc;
    acc.x = ag[0] + bias[og * 4 + 0];
    acc.y = ag[1] + bias[og * 4 + 1];
    acc.z = ag[2] + bias[og * 4 + 2];
    acc.w = ag[3] + bias[og * 4 + 3];
    const float* Rp = root + og * 4;
    #pragma unroll 16
    for (int i = 0; i < FIN; ++i) {
        float xv = xs[vsub][i];
        float4 w = *(const float4*)(Rp + (size_t)i * H1S);
        acc.x += xv * w.x; acc.y += xv * w.y; acc.z += xv * w.z; acc.w += xv * w.w;
    }
    if (valid) {
        ag[0] = fmaxf(acc.x, 0.f);
        ag[1] = fmaxf(acc.y, 0.f);
        ag[2] = fmaxf(acc.z, 0.f);
        ag[3] = fmaxf(acc.w, 0.f);
    }
}

// ---------------- layer-2 finish: agg = agg + x@root + b (no act) ----------------
__global__ __launch_bounds__(256) void finish_l2(const float* __restrict__ x,
                                                 const float* __restrict__ root,
                                                 const float* __restrict__ bias,
                                                 float* __restrict__ agg, int n) {
    __shared__ float xs[32][H1S + 1];
    int tid = threadIdx.x;
    int vsub = tid >> 3, og = tid & 7;
    int v = blockIdx.x * 32 + vsub;
    bool valid = v < n;
    int vv = valid ? v : n - 1;
    #pragma unroll
    for (int i = 0; i < 8; ++i)
        xs[vsub][og + 8 * i] = x[(size_t)vv * H1S + og + 8 * i];
    __syncthreads();
    float* ag = agg + (size_t)vv * H2S + og * 4;
    float4 acc;
    acc.x = ag[0] + bias[og * 4 + 0];
    acc.y = ag[1] + bias[og * 4 + 1];
    acc.z = ag[2] + bias[og * 4 + 2];
    acc.w = ag[3] + bias[og * 4 + 3];
    const float* Rp = root + og * 4;
    #pragma unroll
    for (int i = 0; i < H1S; ++i) {
        float xv = xs[vsub][i];
        float4 w = *(const float4*)(Rp + (size_t)i * H2S);
        acc.x += xv * w.x; acc.y += xv * w.y; acc.z += xv * w.z; acc.w += xv * w.w;
    }
    if (valid) {
        ag[0] = acc.x; ag[1] = acc.y; ag[2] = acc.z; ag[3] = acc.w;
    }
}

// ---------------- embeds: [N,160] = concat(x2_oo[N,32], x2_s[b][N,32] b=0..3) -------
__global__ __launch_bounds__(256) void build_embeds(const float* __restrict__ x2_oo,
                                                    const float* __restrict__ x2_s,
                                                    float* __restrict__ embeds) {
    int t = blockIdx.x * blockDim.x + threadIdx.x;
    if (t >= N_NODES * 160) return;
    int v = t / 160, c = t % 160;
    float val;
    if (c < 32) val = x2_oo[v * 32 + c];
    else {
        int bb = (c - 32) >> 5, cc = (c - 32) & 31;
        val = x2_s[((size_t)bb * N_NODES + v) * 32 + cc];
    }
    embeds[t] = val;
}

// ---------------- gather pair features [B,576] ----------------
__global__ __launch_bounds__(256) void gather_feats(const float* __restrict__ embeds,
                                                    const float* __restrict__ features1,
                                                    const int* __restrict__ idx,
                                                    float* __restrict__ feats) {
    int t = blockIdx.x * blockDim.x + threadIdx.x;
    if (t >= BP * 576) return;
    int b = t / 576, c = t % 576;
    int d1 = idx[b], d2 = idx[BP + b];
    float v;
    if (c < 160)       v = embeds[(size_t)d1 * 160 + c];
    else if (c < 288)  v = features1[(size_t)d1 * FIN + (c - 160)];
    else if (c < 448)  v = embeds[(size_t)d2 * 160 + (c - 288)];
    else               v = features1[(size_t)d2 * FIN + (c - 448)];
    feats[t] = v;
}

// ---------------- MLP GEMM: C = act(A[M,K] @ W[K,N] + b) ----------------
// BM=BN=64, BK=16, 256 threads, 4x4 per thread. ACT: 0=none, 1=elu
template <int ACT>
__global__ __launch_bounds__(256) void mlp_gemm(const float* __restrict__ A,
                                                const float* __restrict__ W,
                                                const float* __restrict__ bias,
                                                float* __restrict__ C,
                                                int M, int Nn, int K) {
    __shared__ float As[64][17];
    __shared__ float Ws[16][65];
    int tid = threadIdx.x;
    int tx = tid & 15, ty = tid >> 4;
    int row0 = blockIdx.x * 64, col0 = blockIdx.y * 64;
    float acc[4][4] = {};
    for (int k0 = 0; k0 < K; k0 += 16) {
        {
            int l = tid * 4;
            int r = l >> 4, c = l & 15;
            const float* Ap = A + (size_t)(row0 + r) * K + k0 + c;
            As[r][c + 0] = Ap[0]; As[r][c + 1] = Ap[1];
            As[r][c + 2] = Ap[2]; As[r][c + 3] = Ap[3];
        }
        {
            int l = tid * 4;
            int r = l >> 6, c = l & 63;
            const float* Wp = W + (size_t)(k0 + r) * Nn + col0 + c;
            #pragma unroll
            for (int j = 0; j < 4; ++j)
                Ws[r][c + j] = (col0 + c + j < Nn) ? Wp[j] : 0.f;
        }
        __syncthreads();
        #pragma unroll
        for (int k = 0; k < 16; ++k) {
            float a[4], b[4];
            #pragma unroll
            for (int i = 0; i < 4; ++i) a[i] = As[ty * 4 + i][k];
            #pragma unroll
            for (int j = 0; j < 4; ++j) b[j] = Ws[k][tx * 4 + j];
            #pragma unroll
            for (int i = 0; i < 4; ++i)
                #pragma unroll
                for (int j = 0; j < 4; ++j) acc[i][j] += a[i] * b[j];
        }
        __syncthreads();
    }
    #pragma unroll
    for (int i = 0; i < 4; ++i) {
        int rr = row0 + ty * 4 + i;
        #pragma unroll
        for (int j = 0; j < 4; ++j) {
            int cc = col0 + tx * 4 + j;
            if (cc < Nn) {
                float v = acc[i][j] + bias[cc];
                if (ACT == 1) v = (v > 0.f) ? v : expm1f(v);
                C[(size_t)rr * Nn + cc] = v;
            }
        }
    }
}

extern "C" void kernel_launch(void* const* d_in, const int* in_sizes, int n_in,
                              void* d_out, int out_size, void* d_ws, size_t ws_size,
                              hipStream_t stream) {
    const float* x_o      = (const float*)d_in[0];
    const int*   ei_o     = (const int*)d_in[1];   // [2, EO]
    const int*   et_o     = (const int*)d_in[2];   // [EO]
    const float* x_s      = (const float*)d_in[3]; // [NB, N, FIN]
    const int*   ei_s     = (const int*)d_in[4];   // [NB, 2, ES]
    const int*   et_s     = (const int*)d_in[5];   // [NB, ES]
    const int*   idx      = (const int*)d_in[6];   // [2, BP]
    const float* features1= (const float*)d_in[7]; // [N, FIN]
    const float* W1       = (const float*)d_in[8];
    const float* root1    = (const float*)d_in[9];
    const float* b1       = (const float*)d_in[10];
    const float* W2       = (const float*)d_in[11];
    const float* root2    = (const float*)d_in[12];
    const float* b2       = (const float*)d_in[13];
    const float* Ws1      = (const float*)d_in[14];
    const float* roots1   = (const float*)d_in[15];
    const float* bs1      = (const float*)d_in[16];
    const float* Ws2      = (const float*)d_in[17];
    const float* roots2   = (const float*)d_in[18];
    const float* bs2      = (const float*)d_in[19];
    const float* mlp_w1   = (const float*)d_in[20];
    const float* mlp_b1   = (const float*)d_in[21];
    const float* mlp_w2   = (const float*)d_in[22];
    const float* mlp_b2   = (const float*)d_in[23];
    const float* mlp_w3   = (const float*)d_in[24];
    const float* mlp_b3   = (const float*)d_in[25];

    // workspace layout (floats). Zeroed region first.
    float* ws = (float*)d_ws;
    float* deg_o  = ws;                                  // N*R
    float* deg_s  = deg_o  + (size_t)N_NODES * RREL;     // 4 * N*R
    float* h1_o   = deg_s  + (size_t)4 * N_NODES * RREL; // N*64
    float* x2_oo  = h1_o   + (size_t)N_NODES * H1S;      // N*32
    float* h1_s   = x2_oo  + (size_t)N_NODES * H2S;      // 4*N*64
    float* x2_s   = h1_s   + (size_t)4 * N_NODES * H1S;  // 4*N*32
    float* embeds = x2_s   + (size_t)4 * N_NODES * H2S;  // N*160
    float* feats  = embeds + (size_t)N_NODES * 160;      // B*576
    float* mh1    = feats  + (size_t)BP * 576;           // B*256
    float* mh2    = mh1    + (size_t)BP * 256;           // B*128

    size_t zero_floats = (size_t)5 * N_NODES * RREL + (size_t)N_NODES * H1S +
                         (size_t)N_NODES * H2S + (size_t)4 * N_NODES * H1S +
                         (size_t)4 * N_NODES * H2S;
    hipMemsetAsync(ws, 0, zero_floats * sizeof(float), stream);

    // ---- degree counts (shared between both layers of each graph) ----
    count_deg<<<(EO + 255) / 256, 256, 0, stream>>>(ei_o + EO, et_o, EO, deg_o);
    for (int b = 0; b < NBR; ++b) {
        count_deg<<<(ES + 255) / 256, 256, 0, stream>>>(
            ei_s + (size_t)b * 2 * ES + ES, et_s + (size_t)b * ES, ES,
            deg_s + (size_t)b * N_NODES * RREL);
    }

    // ---- main encoder ----
    rgcn_msg_l1<<<EO / 16, 256, 0, stream>>>(x_o, ei_o, ei_o + EO, et_o, EO, W1, deg_o, h1_o);
    finish_l1<<<(N_NODES + 15) / 16, 256, 0, stream>>>(x_o, root1, b1, h1_o, N_NODES);
    rgcn_msg_l2<<<EO / 32, 256, 0, stream>>>(h1_o, ei_o, ei_o + EO, et_o, EO, W2, deg_o, x2_oo);
    finish_l2<<<(N_NODES + 31) / 32, 256, 0, stream>>>(h1_o, root2, b2, x2_oo, N_NODES);

    // ---- 4 branch encoders ----
    for (int b = 0; b < NBR; ++b) {
        const float* xb   = x_s + (size_t)b * N_NODES * FIN;
        const int*   srcb = ei_s + (size_t)b * 2 * ES;
        const int*   dstb = srcb + ES;
        const int*   etb  = et_s + (size_t)b * ES;
        const float* degb = deg_s + (size_t)b * N_NODES * RREL;
        float* h1b = h1_s + (size_t)b * N_NODES * H1S;
        float* x2b = x2_s + (size_t)b * N_NODES * H2S;
        rgcn_msg_l1<<<ES / 16, 256, 0, stream>>>(
            xb, srcb, dstb, etb, ES, Ws1 + (size_t)b * RREL * FIN * H1S, degb, h1b);
        finish_l1<<<(N_NODES + 15) / 16, 256, 0, stream>>>(
            xb, roots1 + (size_t)b * FIN * H1S, bs1 + (size_t)b * H1S, h1b, N_NODES);
        rgcn_msg_l2<<<ES / 32, 256, 0, stream>>>(
            h1b, srcb, dstb, etb, ES, Ws2 + (size_t)b * RREL * H1S * H2S, degb, x2b);
        finish_l2<<<(N_NODES + 31) / 32, 256, 0, stream>>>(
            h1b, roots2 + (size_t)b * H1S * H2S, bs2 + (size_t)b * H2S, x2b, N_NODES);
    }

    // ---- head ----
    build_embeds<<<(N_NODES * 160 + 255) / 256, 256, 0, stream>>>(x2_oo, x2_s, embeds);
    gather_feats<<<(BP * 576 + 255) / 256, 256, 0, stream>>>(embeds, features1, idx, feats);
    mlp_gemm<1><<<dim3(BP / 64, (256 + 63) / 64), 256, 0, stream>>>(feats, mlp_w1, mlp_b1, mh1, BP, 256, 576);
    mlp_gemm<1><<<dim3(BP / 64, (128 + 63) / 64), 256, 0, stream>>>(mh1, mlp_w2, mlp_b2, mh2, BP, 128, 256);
    mlp_gemm<0><<<dim3(BP / 64, (65 + 63) / 64), 256, 0, stream>>>(mh2, mlp_w3, mlp_b3, (float*)d_out, BP, 65, 128);
}